// Round 1
// baseline (443.785 us; speedup 1.0000x reference)
//
#include <hip/hip_runtime.h>

// ScatterObservedPorts: out[b, n] = sum_j (node_indices[j]==n) * inputs[b, j]
// Indices are unique by construction (stride-97), so scatter-add == scatter-set.
// Strategy: inverse map in d_ws (map[n] = j or -1), then one fused pass writing
// the whole [B, N] output with coalesced float4 stores (zero or gathered value).
// This is write-BW bound: ~410 MB stores -> ~65 us floor at 6.3 TB/s.

__global__ void init_map_kernel(int* __restrict__ map, int n) {
    int i = blockIdx.x * blockDim.x + threadIdx.x;
    if (i < n) map[i] = -1;
}

__global__ void fill_map_kernel(const int* __restrict__ idx, int k,
                                int* __restrict__ map) {
    int j = blockIdx.x * blockDim.x + threadIdx.x;
    if (j < k) map[idx[j]] = j;
}

__global__ __launch_bounds__(256) void fused_scatter_kernel(
    const float* __restrict__ in,   // [B, K]
    const int*   __restrict__ map,  // [N], -1 or position j
    float*       __restrict__ out,  // [B, N] (trailing unit dim is layout-free)
    int K, int n4)                  // n4 = N/4
{
    int g = blockIdx.x * blockDim.x + threadIdx.x;
    if (g >= n4) return;
    int b = blockIdx.y;

    const int4 m = ((const int4*)map)[g];          // L2-hit after first row
    const float* row = in + (size_t)b * K;

    float4 v = make_float4(0.f, 0.f, 0.f, 0.f);
    if (m.x >= 0) v.x = row[m.x];
    if (m.y >= 0) v.y = row[m.y];
    if (m.z >= 0) v.z = row[m.z];
    if (m.w >= 0) v.w = row[m.w];

    ((float4*)out)[(size_t)b * n4 + g] = v;        // coalesced 16B store
}

extern "C" void kernel_launch(void* const* d_in, const int* in_sizes, int n_in,
                              void* d_out, int out_size, void* d_ws, size_t ws_size,
                              hipStream_t stream) {
    const float* in  = (const float*)d_in[0];
    const int*   idx = (const int*)d_in[1];
    float*       out = (float*)d_out;

    const int K = in_sizes[1];             // 512
    const int B = in_sizes[0] / K;         // 2048
    const int N = out_size / B;            // 50000
    const int n4 = N / 4;                  // 12500 (N divisible by 4)

    int* map = (int*)d_ws;                 // needs N*4 = 200 KB of workspace

    init_map_kernel<<<(N + 255) / 256, 256, 0, stream>>>(map, N);
    fill_map_kernel<<<(K + 255) / 256, 256, 0, stream>>>(idx, K, map);

    dim3 grid((n4 + 255) / 256, B);
    fused_scatter_kernel<<<grid, 256, 0, stream>>>(in, map, out, K, n4);
}

// Round 3
// 436.403 us; speedup vs baseline: 1.0169x; 1.0169x over previous
//
#include <hip/hip_runtime.h>

// ScatterObservedPorts: out[b, n] = sum_j (node_indices[j]==n) * inputs[b, j]
// Indices unique by construction (stride-97) -> scatter-set == scatter-add.
//
// Single fused pass writes every output element exactly once (coalesced
// 16B nt-stores). Inverse map (map[n] = j or -1) lives in d_ws.
// ROWS=8 unroll: each thread loads its map int4 ONCE and reuses it across
// 8 consecutive rows (cuts map L2 traffic 8x); nontemporal stores keep the
// 410 MB output stream from evicting the map/input out of the per-XCD L2.

#define ROWS 8

typedef float v4f __attribute__((ext_vector_type(4)));  // native vec for nt-store
typedef int   v4i __attribute__((ext_vector_type(4)));

__global__ void init_map_kernel(int* __restrict__ map, int n) {
    int i = blockIdx.x * blockDim.x + threadIdx.x;
    if (i < n) map[i] = -1;
}

__global__ void fill_map_kernel(const int* __restrict__ idx, int k,
                                int* __restrict__ map) {
    int j = blockIdx.x * blockDim.x + threadIdx.x;
    if (j < k) map[idx[j]] = j;
}

__global__ __launch_bounds__(256) void fused_scatter_rows_kernel(
    const float* __restrict__ in,   // [B, K]
    const int*   __restrict__ map,  // [N], -1 or position j
    float*       __restrict__ out,  // [B, N]
    int K, int n4, int B)           // n4 = N/4
{
    int g = blockIdx.x * 256 + threadIdx.x;
    if (g >= n4) return;
    int b0 = blockIdx.y * ROWS;

    const v4i m = ((const v4i*)map)[g];        // one map load per 8 rows
    v4f* p = (v4f*)out + (size_t)b0 * n4 + g;
    const float* row = in + (size_t)b0 * K;

    int nr = B - b0;
    if (nr >= ROWS) {
#pragma unroll
        for (int r = 0; r < ROWS; ++r) {
            v4f v = (v4f)(0.f);
            if (m.x >= 0) v.x = row[m.x];
            if (m.y >= 0) v.y = row[m.y];
            if (m.z >= 0) v.z = row[m.z];
            if (m.w >= 0) v.w = row[m.w];
            __builtin_nontemporal_store(v, p); // nt: don't pollute L2
            p += n4; row += K;
        }
    } else {
        for (int r = 0; r < nr; ++r) {
            v4f v = (v4f)(0.f);
            if (m.x >= 0) v.x = row[m.x];
            if (m.y >= 0) v.y = row[m.y];
            if (m.z >= 0) v.z = row[m.z];
            if (m.w >= 0) v.w = row[m.w];
            __builtin_nontemporal_store(v, p);
            p += n4; row += K;
        }
    }
}

extern "C" void kernel_launch(void* const* d_in, const int* in_sizes, int n_in,
                              void* d_out, int out_size, void* d_ws, size_t ws_size,
                              hipStream_t stream) {
    const float* in  = (const float*)d_in[0];
    const int*   idx = (const int*)d_in[1];
    float*       out = (float*)d_out;

    const int K = in_sizes[1];             // 512
    const int B = in_sizes[0] / K;         // 2048
    const int N = out_size / B;            // 50000
    const int n4 = N / 4;                  // 12500

    int* map = (int*)d_ws;                 // N*4 = 200 KB of workspace

    init_map_kernel<<<(N + 255) / 256, 256, 0, stream>>>(map, N);
    fill_map_kernel<<<(K + 255) / 256, 256, 0, stream>>>(idx, K, map);

    dim3 grid((n4 + 255) / 256, (B + ROWS - 1) / ROWS);
    fused_scatter_rows_kernel<<<grid, 256, 0, stream>>>(in, map, out, K, n4, B);
}